// Round 5
// baseline (1022.593 us; speedup 1.0000x reference)
//
#include <hip/hip_runtime.h>
#include <math.h>

#define NN 10000
#define EE 320000
#define PP 200000

#define GLOAD_LDS16(gsrc, ldst)                                                        \
    __builtin_amdgcn_global_load_lds((const __attribute__((address_space(1))) void*)(gsrc), \
                                     (__attribute__((address_space(3))) void*)(ldst), 16, 0, 0)

// ---------------- degree / norm ----------------
__global__ void k_deg_count(const int* __restrict__ dst, int* __restrict__ degi) {
    int e = blockIdx.x * blockDim.x + threadIdx.x;
    if (e < EE) atomicAdd(&degi[dst[e]], 1);
}

__global__ void k_dinv(const int* __restrict__ degi, float* __restrict__ dinv) {
    int n = blockIdx.x * blockDim.x + threadIdx.x;
    if (n < NN) dinv[n] = rsqrtf((float)(degi[n] + 1));  // +1 self loop
}

// ---------------- GEMM1: h1_pre = x @ W1  (10000x10000 @ 10000x32) ----------------
// Double-buffered global_load_lds pipeline for x only. W1 (1.28 MB, L2-resident,
// identical stream for every block) is read directly from global in the compute
// loop: drops LDS reads per kk4 from 8 -> 4 and LDS/block 40 -> 32 KB (5 blocks/CU).
// x tile [128][32] linear LDS, XOR-swizzled via pre-swizzled global source.
// Grid (79 row-blocks, 16 K-splits); 256 thr; thread = 4 rows x 4 cols.
__global__ __launch_bounds__(256, 5) void k_gemm1(const float* __restrict__ x,
                                                  const float* __restrict__ W1,
                                                  const float* __restrict__ zp,
                                                  float* __restrict__ h1_pre) {
    __shared__ float xs[2][128][32];   // 16 KB each
    const int tid = threadIdx.x;
    const int lane = tid & 63;
    const int w = tid >> 6;            // wave id 0..3
    const int lr = lane >> 3;          // row-within-8 of this lane
    const int s = lane & 7;            // 16B slot of this lane
    const int tx = tid & 7;            // col-group (4 cols)
    const int ty = tid >> 3;           // row-group
    const int sw = ty & 7;             // compute-side XOR key
    const int row0 = blockIdx.x * 128;
    const int k_begin = blockIdx.y * 640;
    const int k_end = min(NN, k_begin + 640);
    const int span = k_end - k_begin;
    const int nfull = span >> 5;
    const int ntiles = nfull + ((span & 31) ? 1 : 0);
    const long NN2 = (long)NN * NN;

    float acc[4][4];
#pragma unroll
    for (int i = 0; i < 4; ++i)
#pragma unroll
        for (int j = 0; j < 4; ++j) acc[i][j] = 0.f;

    // ---- stage one 32-K x tile into buffer `buf` (async, no waits here) ----
    auto stage = [&](int buf, int k0) {
#pragma unroll
        for (int j = 0; j < 4; ++j) {
            int r_local = w * 32 + j * 8 + lr;
            int c4 = s ^ (r_local & 7);                       // pre-swizzled source slot
            long flat = (long)(row0 + r_local) * NN + k0 + c4 * 4;
            const float* src = (flat + 4 <= NN2) ? (x + flat) : zp;
            GLOAD_LDS16(src, &xs[buf][w * 32 + j * 8][0]);
        }
    };

    stage(0, k_begin);
    __syncthreads();

    int cur = 0;
    for (int t = 0; t < ntiles; ++t) {
        const int k0 = k_begin + t * 32;
        if (t + 1 < ntiles) stage(cur ^ 1, k0 + 32);
        if (t < nfull) {
            // ---- full tile, unguarded W ----
#pragma unroll
            for (int kk4 = 0; kk4 < 8; ++kk4) {
                const float* wrow = &W1[(long)(k0 + kk4 * 4) * 32 + tx * 4];
                float4 wv0 = *(const float4*)(wrow);
                float4 wv1 = *(const float4*)(wrow + 32);
                float4 wv2 = *(const float4*)(wrow + 64);
                float4 wv3 = *(const float4*)(wrow + 96);
                const int slot = (kk4 ^ sw) * 4;              // un-swizzle on read
#pragma unroll
                for (int i = 0; i < 4; ++i) {
                    float4 xv = *(const float4*)&xs[cur][ty + i * 32][slot];
                    acc[i][0] += xv.x * wv0.x + xv.y * wv1.x + xv.z * wv2.x + xv.w * wv3.x;
                    acc[i][1] += xv.x * wv0.y + xv.y * wv1.y + xv.z * wv2.y + xv.w * wv3.y;
                    acc[i][2] += xv.x * wv0.z + xv.y * wv1.z + xv.z * wv2.z + xv.w * wv3.z;
                    acc[i][3] += xv.x * wv0.w + xv.y * wv1.w + xv.z * wv2.w + xv.w * wv3.w;
                }
            }
        } else {
            // ---- partial tail tile (last K-split only): guard W per k-row ----
            const float4 z4 = make_float4(0.f, 0.f, 0.f, 0.f);
#pragma unroll
            for (int kk4 = 0; kk4 < 8; ++kk4) {
                int gk = k0 + kk4 * 4;
                const float* wrow = &W1[(long)gk * 32 + tx * 4];
                float4 wv0 = (gk + 0 < k_end) ? *(const float4*)(wrow)      : z4;
                float4 wv1 = (gk + 1 < k_end) ? *(const float4*)(wrow + 32) : z4;
                float4 wv2 = (gk + 2 < k_end) ? *(const float4*)(wrow + 64) : z4;
                float4 wv3 = (gk + 3 < k_end) ? *(const float4*)(wrow + 96) : z4;
                const int slot = (kk4 ^ sw) * 4;
#pragma unroll
                for (int i = 0; i < 4; ++i) {
                    float4 xv = *(const float4*)&xs[cur][ty + i * 32][slot];
                    acc[i][0] += xv.x * wv0.x + xv.y * wv1.x + xv.z * wv2.x + xv.w * wv3.x;
                    acc[i][1] += xv.x * wv0.y + xv.y * wv1.y + xv.z * wv2.y + xv.w * wv3.y;
                    acc[i][2] += xv.x * wv0.z + xv.y * wv1.z + xv.z * wv2.z + xv.w * wv3.z;
                    acc[i][3] += xv.x * wv0.w + xv.y * wv1.w + xv.z * wv2.w + xv.w * wv3.w;
                }
            }
        }
        __syncthreads();   // drains vmcnt(0): next tile staged; cur buffer free
        cur ^= 1;
    }

    // ---- epilogue: atomic accumulate K-split partials ----
#pragma unroll
    for (int i = 0; i < 4; ++i) {
        int grow = row0 + ty + i * 32;
        if (grow < NN) {
#pragma unroll
            for (int j = 0; j < 4; ++j)
                atomicAdd(&h1_pre[grow * 32 + tx * 4 + j], acc[i][j]);
        }
    }
}

// ---------------- aggregation layer 1 (32 feats) ----------------
__global__ void k_selfinit1(const float* __restrict__ h1_pre, const float* __restrict__ dinv,
                            float* __restrict__ out1) {
    int t = blockIdx.x * blockDim.x + threadIdx.x;
    if (t < NN * 32) {
        int n = t >> 5;
        float di = dinv[n];
        out1[t] = di * di * h1_pre[t];
    }
}

__global__ void k_scatter1(const int* __restrict__ src, const int* __restrict__ dst,
                           const float* __restrict__ dinv, const float* __restrict__ h1_pre,
                           float* __restrict__ out1) {
    int t = blockIdx.x * blockDim.x + threadIdx.x;
    if (t >= EE * 32) return;
    int e = t >> 5, c = t & 31;
    int s = src[e], d = dst[e];
    float nrm = dinv[s] * dinv[d];
    atomicAdd(&out1[d * 32 + c], h1_pre[s * 32 + c] * nrm);
}

__global__ void k_bias_relu1(float* __restrict__ out1, const float* __restrict__ b1) {
    int t = blockIdx.x * blockDim.x + threadIdx.x;
    if (t < NN * 32) out1[t] = fmaxf(out1[t] + b1[t & 31], 0.f);
}

// ---------------- GEMM2: h2_pre = out1 @ W2  (10000x32 @ 32x16) ----------------
__global__ __launch_bounds__(256) void k_gemm2(const float* __restrict__ out1,
                                               const float* __restrict__ W2,
                                               float* __restrict__ h2_pre) {
    __shared__ float w2s[512];
    int tid = threadIdx.x;
    w2s[tid] = W2[tid & 511];
    if (tid < 256) w2s[256 + tid] = W2[256 + tid];
    __syncthreads();
    int c = tid & 15, yloc = tid >> 4;
    int n = blockIdx.x * 16 + yloc;
    if (n < NN) {
        float a = 0.f;
#pragma unroll
        for (int k = 0; k < 32; ++k) a += out1[n * 32 + k] * w2s[k * 16 + c];
        h2_pre[n * 16 + c] = a;
    }
}

// ---------------- aggregation layer 2 (16 feats) ----------------
__global__ void k_selfinit2(const float* __restrict__ h2_pre, const float* __restrict__ dinv,
                            float* __restrict__ out2) {
    int t = blockIdx.x * blockDim.x + threadIdx.x;
    if (t < NN * 16) {
        int n = t >> 4;
        float di = dinv[n];
        out2[t] = di * di * h2_pre[t];
    }
}

__global__ void k_scatter2(const int* __restrict__ src, const int* __restrict__ dst,
                           const float* __restrict__ dinv, const float* __restrict__ h2_pre,
                           float* __restrict__ out2) {
    int t = blockIdx.x * blockDim.x + threadIdx.x;
    if (t >= EE * 16) return;
    int e = t >> 4, c = t & 15;
    int s = src[e], d = dst[e];
    float nrm = dinv[s] * dinv[d];
    atomicAdd(&out2[d * 16 + c], h2_pre[s * 16 + c] * nrm);
}

// ---------------- final: per-node partial dots with Wfc ----------------
__global__ void k_final2(const float* __restrict__ out2, const float* __restrict__ b2,
                         const float* __restrict__ Wfc, float* __restrict__ s_arr,
                         float* __restrict__ t_arr) {
    int n = blockIdx.x * blockDim.x + threadIdx.x;
    if (n >= NN) return;
    float s = 0.f, t = 0.f;
#pragma unroll
    for (int c = 0; c < 16; ++c) {
        float v = out2[n * 16 + c] + b2[c];
        s += v * Wfc[c];
        t += v * Wfc[16 + c];
    }
    s_arr[n] = s;
    t_arr[n] = t;
}

// ---------------- pair scoring ----------------
__global__ void k_pairs(const int* __restrict__ pair, const float* __restrict__ s_arr,
                        const float* __restrict__ t_arr, const float* __restrict__ bfc,
                        float* __restrict__ out) {
    int p = blockIdx.x * blockDim.x + threadIdx.x;
    if (p >= PP) return;
    const int2 ab = ((const int2*)pair)[p];
    float z = s_arr[ab.x] + t_arr[ab.y] + bfc[0];
    out[p] = 1.f / (1.f + expf(-z));
}

extern "C" void kernel_launch(void* const* d_in, const int* in_sizes, int n_in,
                              void* d_out, int out_size, void* d_ws, size_t ws_size,
                              hipStream_t stream) {
    const float* x    = (const float*)d_in[0];
    const int*   edge = (const int*)d_in[1];   // [2][E]
    const int*   pair = (const int*)d_in[2];   // [P][2]
    const float* W1   = (const float*)d_in[3];
    const float* b1   = (const float*)d_in[4];
    const float* W2   = (const float*)d_in[5];
    const float* b2   = (const float*)d_in[6];
    const float* Wfc  = (const float*)d_in[7];
    const float* bfc  = (const float*)d_in[8];
    float* out = (float*)d_out;
    float* ws  = (float*)d_ws;

    const int* src = edge;
    const int* dst = edge + EE;

    // workspace layout (floats)
    int*   degi   = (int*)ws;            // N
    float* dinv   = ws + NN;             // N
    float* h1_pre = ws + 2 * NN;         // 32N
    float* out1   = ws + 34 * NN;        // 32N
    float* h2_pre = ws + 66 * NN;        // 16N
    float* out2   = ws + 82 * NN;        // 16N
    float* s_arr  = ws + 98 * NN;        // N
    float* t_arr  = ws + 99 * NN;        // N
    float* zp     = ws + 100 * NN;       // 256 floats zero page

    hipMemsetAsync(degi, 0, NN * sizeof(int), stream);
    hipMemsetAsync(h1_pre, 0, NN * 32 * sizeof(float), stream);
    hipMemsetAsync(zp, 0, 1024, stream);

    k_deg_count<<<(EE + 255) / 256, 256, 0, stream>>>(dst, degi);
    k_dinv<<<(NN + 255) / 256, 256, 0, stream>>>(degi, dinv);

    k_gemm1<<<dim3(79, 16), 256, 0, stream>>>(x, W1, zp, h1_pre);

    k_selfinit1<<<(NN * 32 + 255) / 256, 256, 0, stream>>>(h1_pre, dinv, out1);
    k_scatter1<<<(EE * 32 + 255) / 256, 256, 0, stream>>>(src, dst, dinv, h1_pre, out1);
    k_bias_relu1<<<(NN * 32 + 255) / 256, 256, 0, stream>>>(out1, b1);

    k_gemm2<<<(NN + 15) / 16, 256, 0, stream>>>(out1, W2, h2_pre);

    k_selfinit2<<<(NN * 16 + 255) / 256, 256, 0, stream>>>(h2_pre, dinv, out2);
    k_scatter2<<<(EE * 16 + 255) / 256, 256, 0, stream>>>(src, dst, dinv, h2_pre, out2);

    k_final2<<<(NN + 255) / 256, 256, 0, stream>>>(out2, b2, Wfc, s_arr, t_arr);
    k_pairs<<<(PP + 255) / 256, 256, 0, stream>>>(pair, s_arr, t_arr, bfc, out);
}

// Round 6
// 204.434 us; speedup vs baseline: 5.0021x; 5.0021x over previous
//
#include <hip/hip_runtime.h>
#include <math.h>

#define NN 10000
#define EE 320000
#define PP 200000

typedef __attribute__((ext_vector_type(8))) short bf8v;   // 8 bf16 (A/B frag)
typedef __attribute__((ext_vector_type(4))) float f4v;    // 4 f32  (C/D frag)

#define GLOAD_LDS16(gsrc, ldst)                                                        \
    __builtin_amdgcn_global_load_lds((const __attribute__((address_space(1))) void*)(gsrc), \
                                     (__attribute__((address_space(3))) void*)(ldst), 16, 0, 0)

// RTNE fp32 -> bf16 (finite inputs only)
__device__ __forceinline__ ushort f2bf(float f) {
    uint u = __float_as_uint(f);
    return (ushort)((u + 0x7fffu + ((u >> 16) & 1u)) >> 16);
}

// ---------------- degree / norm ----------------
__global__ void k_deg_count(const int* __restrict__ dst, int* __restrict__ degi) {
    int e = blockIdx.x * blockDim.x + threadIdx.x;
    if (e < EE) atomicAdd(&degi[dst[e]], 1);
}

__global__ void k_dinv(const int* __restrict__ degi, float* __restrict__ dinv) {
    int n = blockIdx.x * blockDim.x + threadIdx.x;
    if (n < NN) dinv[n] = rsqrtf((float)(degi[n] + 1));  // +1 self loop
}

// ---------------- GEMM1: h1_pre = x @ W1 (10000x10000 @ 10000x32), bf16 MFMA ----------------
// x staged fp32 via global_load_lds (R3-proven path, source-preswizzled slots);
// converted to bf16 IN REGISTERS after ds_read (no vmcnt in compute phase).
// W1 reg-staged -> bf16 -> transposed LDS tile wt[col][k] (slot-swizzled).
// Per K-tile per wave: 4 float4 LDS reads (A) + 2 b128 (B) + 4 MFMA 16x16x32_bf16.
// Grid (79 row-blocks of 128, 16 K-splits of 640); 256 thr; wave w owns rows w*32..+32.
__global__ __launch_bounds__(256) void k_gemm1(const float* __restrict__ x,
                                               const float* __restrict__ W1,
                                               const float* __restrict__ zp,
                                               float* __restrict__ h1_pre) {
    __shared__ __align__(16) float  xs[2][128][32];   // 16 KB each (fp32, slot-swizzled)
    __shared__ __align__(16) ushort wt[2][32][32];    // 2 KB each ([col][k] bf16, slot-swizzled)
    const int tid = threadIdx.x;
    const int lane = tid & 63;
    const int w = tid >> 6;            // wave id 0..3
    const int lr = lane >> 3;          // staging: row-within-8
    const int s = lane & 7;            // staging: 16B slot
    const int row0 = blockIdx.x * 128;
    const int k_begin = blockIdx.y * 640;
    const int k_end = min(NN, k_begin + 640);
    const int ntiles = (k_end - k_begin + 31) >> 5;
    const long NN2 = (long)NN * NN;

    // W staging: thread -> (col wc, k-quad wkq)
    const int wc = tid & 31;
    const int wkq = tid >> 5;          // 0..7 (4 k each)
    const int wt_off = wc * 32 + ((((wkq >> 1) ^ (wc & 3))) << 3) + ((wkq & 1) << 2); // ushorts

    // fragment geometry
    const int fl = lane & 15;
    const int khi = lane >> 4;         // 0..3

    f4v acc[2][2];
#pragma unroll
    for (int a = 0; a < 2; ++a)
#pragma unroll
        for (int b = 0; b < 2; ++b) acc[a][b] = (f4v){0.f, 0.f, 0.f, 0.f};

    auto stage_x = [&](int buf, int k0) {
#pragma unroll
        for (int j = 0; j < 4; ++j) {
            int r_local = w * 32 + j * 8 + lr;
            int c4 = s ^ (r_local & 7);                       // pre-swizzled source slot
            long flat = (long)(row0 + r_local) * NN + k0 + c4 * 4;
            const float* src = (flat + 4 <= NN2) ? (x + flat) : zp;
            GLOAD_LDS16(src, &xs[buf][w * 32 + j * 8][0]);
        }
    };
    auto wload = [&](int k0, float* wr) {
#pragma unroll
        for (int i = 0; i < 4; ++i) {
            int gk = k0 + wkq * 4 + i;
            wr[i] = (gk < k_end) ? W1[(long)gk * 32 + wc] : 0.f;   // zero-pad OOB k
        }
    };
    auto wstore = [&](int buf, const float* wr) {
        union { uint2 d; ushort u[4]; } p;
        p.u[0] = f2bf(wr[0]); p.u[1] = f2bf(wr[1]);
        p.u[2] = f2bf(wr[2]); p.u[3] = f2bf(wr[3]);
        *(uint2*)((ushort*)&wt[buf][0][0] + wt_off) = p.d;
    };
    auto compute = [&](int buf) {
        // B fragments (bf16 direct): col = ct*16+fl, k = khi*8..+8 -> one b128 each
        bf8v bfr[2];
        const int nb = fl & 3;
#pragma unroll
        for (int ct = 0; ct < 2; ++ct)
            bfr[ct] = *(const bf8v*)&wt[buf][ct * 16 + fl][(khi ^ nb) << 3];
#pragma unroll
        for (int rt = 0; rt < 2; ++rt) {
            const int row = w * 32 + rt * 16 + fl;
            const float4* xr = (const float4*)&xs[buf][row][0];
            float4 f0 = xr[(khi * 2) ^ (row & 7)];            // k = khi*8 .. +4
            float4 f1 = xr[(khi * 2 + 1) ^ (row & 7)];        // k = khi*8+4 .. +8
            union { bf8v v; ushort u[8]; } a;
            a.u[0] = f2bf(f0.x); a.u[1] = f2bf(f0.y); a.u[2] = f2bf(f0.z); a.u[3] = f2bf(f0.w);
            a.u[4] = f2bf(f1.x); a.u[5] = f2bf(f1.y); a.u[6] = f2bf(f1.z); a.u[7] = f2bf(f1.w);
#pragma unroll
            for (int ct = 0; ct < 2; ++ct)
                acc[rt][ct] = __builtin_amdgcn_mfma_f32_16x16x32_bf16(a.v, bfr[ct], acc[rt][ct], 0, 0, 0);
        }
    };

    // prologue: tile 0
    float wr0[4], wr1[4];
    wload(k_begin, wr0);
    stage_x(0, k_begin);
    wstore(0, wr0);
    __syncthreads();

    int buf = 0;
    for (int t = 0; t < ntiles; ++t) {
        const int k0n = k_begin + (t + 1) * 32;
        if (t + 1 < ntiles) { wload(k0n, wr1); stage_x(buf ^ 1, k0n); }
        compute(buf);                          // LDS + VALU + MFMA only: no vmcnt waits
        if (t + 1 < ntiles) wstore(buf ^ 1, wr1);
        __syncthreads();                       // single vmcnt drain point per tile
        buf ^= 1;
    }

    // epilogue: C/D layout col=lane&15, row=(lane>>4)*4+reg (m89-verified)
#pragma unroll
    for (int rt = 0; rt < 2; ++rt) {
        const int gbase = row0 + w * 32 + rt * 16 + khi * 4;
#pragma unroll
        for (int ct = 0; ct < 2; ++ct) {
            const int col = ct * 16 + fl;
#pragma unroll
            for (int r = 0; r < 4; ++r) {
                const int g = gbase + r;
                if (g < NN) atomicAdd(&h1_pre[g * 32 + col], acc[rt][ct][r]);
            }
        }
    }
}

// ---------------- aggregation layer 1 (32 feats) ----------------
__global__ void k_selfinit1(const float* __restrict__ h1_pre, const float* __restrict__ dinv,
                            float* __restrict__ out1) {
    int t = blockIdx.x * blockDim.x + threadIdx.x;
    if (t < NN * 32) {
        int n = t >> 5;
        float di = dinv[n];
        out1[t] = di * di * h1_pre[t];
    }
}

__global__ void k_scatter1(const int* __restrict__ src, const int* __restrict__ dst,
                           const float* __restrict__ dinv, const float* __restrict__ h1_pre,
                           float* __restrict__ out1) {
    int t = blockIdx.x * blockDim.x + threadIdx.x;
    if (t >= EE * 32) return;
    int e = t >> 5, c = t & 31;
    int s = src[e], d = dst[e];
    float nrm = dinv[s] * dinv[d];
    atomicAdd(&out1[d * 32 + c], h1_pre[s * 32 + c] * nrm);
}

__global__ void k_bias_relu1(float* __restrict__ out1, const float* __restrict__ b1) {
    int t = blockIdx.x * blockDim.x + threadIdx.x;
    if (t < NN * 32) out1[t] = fmaxf(out1[t] + b1[t & 31], 0.f);
}

// ---------------- GEMM2: h2_pre = out1 @ W2  (10000x32 @ 32x16), fp32 ----------------
__global__ __launch_bounds__(256) void k_gemm2(const float* __restrict__ out1,
                                               const float* __restrict__ W2,
                                               float* __restrict__ h2_pre) {
    __shared__ float w2s[512];
    int tid = threadIdx.x;
    w2s[tid] = W2[tid & 511];
    if (tid < 256) w2s[256 + tid] = W2[256 + tid];
    __syncthreads();
    int c = tid & 15, yloc = tid >> 4;
    int n = blockIdx.x * 16 + yloc;
    if (n < NN) {
        float a = 0.f;
#pragma unroll
        for (int k = 0; k < 32; ++k) a += out1[n * 32 + k] * w2s[k * 16 + c];
        h2_pre[n * 16 + c] = a;
    }
}

// ---------------- aggregation layer 2 (16 feats) ----------------
__global__ void k_selfinit2(const float* __restrict__ h2_pre, const float* __restrict__ dinv,
                            float* __restrict__ out2) {
    int t = blockIdx.x * blockDim.x + threadIdx.x;
    if (t < NN * 16) {
        int n = t >> 4;
        float di = dinv[n];
        out2[t] = di * di * h2_pre[t];
    }
}

__global__ void k_scatter2(const int* __restrict__ src, const int* __restrict__ dst,
                           const float* __restrict__ dinv, const float* __restrict__ h2_pre,
                           float* __restrict__ out2) {
    int t = blockIdx.x * blockDim.x + threadIdx.x;
    if (t >= EE * 16) return;
    int e = t >> 4, c = t & 15;
    int s = src[e], d = dst[e];
    float nrm = dinv[s] * dinv[d];
    atomicAdd(&out2[d * 16 + c], h2_pre[s * 16 + c] * nrm);
}

// ---------------- final: per-node partial dots with Wfc ----------------
__global__ void k_final2(const float* __restrict__ out2, const float* __restrict__ b2,
                         const float* __restrict__ Wfc, float* __restrict__ s_arr,
                         float* __restrict__ t_arr) {
    int n = blockIdx.x * blockDim.x + threadIdx.x;
    if (n >= NN) return;
    float s = 0.f, t = 0.f;
#pragma unroll
    for (int c = 0; c < 16; ++c) {
        float v = out2[n * 16 + c] + b2[c];
        s += v * Wfc[c];
        t += v * Wfc[16 + c];
    }
    s_arr[n] = s;
    t_arr[n] = t;
}

// ---------------- pair scoring ----------------
__global__ void k_pairs(const int* __restrict__ pair, const float* __restrict__ s_arr,
                        const float* __restrict__ t_arr, const float* __restrict__ bfc,
                        float* __restrict__ out) {
    int p = blockIdx.x * blockDim.x + threadIdx.x;
    if (p >= PP) return;
    const int2 ab = ((const int2*)pair)[p];
    float z = s_arr[ab.x] + t_arr[ab.y] + bfc[0];
    out[p] = 1.f / (1.f + expf(-z));
}

extern "C" void kernel_launch(void* const* d_in, const int* in_sizes, int n_in,
                              void* d_out, int out_size, void* d_ws, size_t ws_size,
                              hipStream_t stream) {
    const float* x    = (const float*)d_in[0];
    const int*   edge = (const int*)d_in[1];   // [2][E]
    const int*   pair = (const int*)d_in[2];   // [P][2]
    const float* W1   = (const float*)d_in[3];
    const float* b1   = (const float*)d_in[4];
    const float* W2   = (const float*)d_in[5];
    const float* b2   = (const float*)d_in[6];
    const float* Wfc  = (const float*)d_in[7];
    const float* bfc  = (const float*)d_in[8];
    float* out = (float*)d_out;
    float* ws  = (float*)d_ws;

    const int* src = edge;
    const int* dst = edge + EE;

    // workspace layout (floats)
    int*   degi   = (int*)ws;            // N
    float* dinv   = ws + NN;             // N
    float* h1_pre = ws + 2 * NN;         // 32N
    float* out1   = ws + 34 * NN;        // 32N
    float* h2_pre = ws + 66 * NN;        // 16N
    float* out2   = ws + 82 * NN;        // 16N
    float* s_arr  = ws + 98 * NN;        // N
    float* t_arr  = ws + 99 * NN;        // N
    float* zp     = ws + 100 * NN;       // 256 floats zero page

    hipMemsetAsync(degi, 0, NN * sizeof(int), stream);
    hipMemsetAsync(h1_pre, 0, NN * 32 * sizeof(float), stream);
    hipMemsetAsync(zp, 0, 1024, stream);

    k_deg_count<<<(EE + 255) / 256, 256, 0, stream>>>(dst, degi);
    k_dinv<<<(NN + 255) / 256, 256, 0, stream>>>(degi, dinv);

    k_gemm1<<<dim3(79, 16), 256, 0, stream>>>(x, W1, zp, h1_pre);

    k_selfinit1<<<(NN * 32 + 255) / 256, 256, 0, stream>>>(h1_pre, dinv, out1);
    k_scatter1<<<(EE * 32 + 255) / 256, 256, 0, stream>>>(src, dst, dinv, h1_pre, out1);
    k_bias_relu1<<<(NN * 32 + 255) / 256, 256, 0, stream>>>(out1, b1);

    k_gemm2<<<(NN + 15) / 16, 256, 0, stream>>>(out1, W2, h2_pre);

    k_selfinit2<<<(NN * 16 + 255) / 256, 256, 0, stream>>>(h2_pre, dinv, out2);
    k_scatter2<<<(EE * 16 + 255) / 256, 256, 0, stream>>>(src, dst, dinv, h2_pre, out2);

    k_final2<<<(NN + 255) / 256, 256, 0, stream>>>(out2, b2, Wfc, s_arr, t_arr);
    k_pairs<<<(PP + 255) / 256, 256, 0, stream>>>(pair, s_arr, t_arr, bfc, out);
}